// Round 4
// baseline (419.028 us; speedup 1.0000x reference)
//
#include <hip/hip_runtime.h>
#include <hip/hip_bf16.h>

constexpr int kD  = 1024;
constexpr int kH  = 16;
constexpr int kHD = 64;
constexpr int kS  = 64;
constexpr int kE  = 16;
constexpr int kB  = 32;
constexpr int kSB = kS * kB;   // 2048 (s,b) pairs

typedef __attribute__((ext_vector_type(8))) short bfvec8;   // 8 bf16 (4 VGPRs)
typedef __attribute__((ext_vector_type(4))) float fvec4;    // MFMA acc

struct __align__(8)  bf4  { __hip_bfloat16 v[4]; };
struct __align__(16) bf8v { __hip_bfloat16 v[8]; };

// ---------------- tiny precompute kernels ----------------

// out[j] = (dot(Wmat[j,:], vec) + bias[j]) * scale   -- one block per row j
__global__ __launch_bounds__(256) void k_rowdot(const float* __restrict__ Wmat,
                                                const float* __restrict__ vec,
                                                const float* __restrict__ bias,
                                                float scale, float* __restrict__ outv) {
  int j = blockIdx.x;
  int t = threadIdx.x;
  const float4* w4 = (const float4*)(Wmat + (size_t)j * kD);
  const float4* v4 = (const float4*)vec;
  float4 a = w4[t], b = v4[t];
  float acc = a.x * b.x + a.y * b.y + a.z * b.z + a.w * b.w;
  #pragma unroll
  for (int o = 32; o >= 1; o >>= 1) acc += __shfl_xor(acc, o);
  __shared__ float red[4];
  if ((t & 63) == 0) red[t >> 6] = acc;
  __syncthreads();
  if (t == 0) outv[j] = (red[0] + red[1] + red[2] + red[3] + bias[j]) * scale;
}

// wmat[h,d] = sum_j qs[h*64+j] * Wk_in[h*64+j, d]   (rows 0..15 of 64-row buf)
__global__ __launch_bounds__(256) void k_w(const float* __restrict__ qs,
                                           const float* __restrict__ Wk_in,
                                           float* __restrict__ wmat) {
  int tid = blockIdx.x * 256 + threadIdx.x;
  int h = tid >> 10, d = tid & (kD - 1);
  float acc = 0.f;
  #pragma unroll 8
  for (int j = 0; j < kHD; j++)
    acc = fmaf(qs[h * kHD + j], Wk_in[(size_t)(h * kHD + j) * kD + d], acc);
  wmat[(size_t)h * kD + d] = acc;
}

// cvec[h] = dot(wmat[h,:], bk_lin) + dot(qs[hslice], bk_in[hslice])
__global__ __launch_bounds__(256) void k_c(const float* __restrict__ wmat,
                                           const float* __restrict__ bk_lin,
                                           const float* __restrict__ qs,
                                           const float* __restrict__ bk_in,
                                           float* __restrict__ cvec) {
  int t = threadIdx.x;
  int h = t >> 4, l = t & 15;
  float acc = 0.f;
  for (int d = l; d < kD; d += 16) acc += wmat[h * kD + d] * bk_lin[d];
  for (int j = l; j < kHD; j += 16) acc += qs[h * kHD + j] * bk_in[h * kHD + j];
  #pragma unroll
  for (int o = 8; o >= 1; o >>= 1) acc += __shfl_xor(acc, o, 16);
  if (l == 0) cvec[h] = acc;
}

// out_bf[c][k] = bf16(in[k][c])   (transpose + convert, 1024x1024)
__global__ void k_transpose_cvt(const float* __restrict__ in,
                                __hip_bfloat16* __restrict__ out) {
  __shared__ float tile[32][33];
  int x = blockIdx.x * 32 + threadIdx.x;
  int y0 = blockIdx.y * 32;
  for (int i = threadIdx.y; i < 32; i += 8)
    tile[i][threadIdx.x] = in[(size_t)(y0 + i) * kD + x];
  __syncthreads();
  int xo = blockIdx.y * 32 + threadIdx.x;
  int yo0 = blockIdx.x * 32;
  for (int i = threadIdx.y; i < 32; i += 8)
    out[(size_t)(yo0 + i) * kD + xo] = __float2bfloat16(tile[threadIdx.x][i]);
}

// plain f32 -> bf16 convert, 4 elems/thread
__global__ __launch_bounds__(256) void k_cvt(const float* __restrict__ in,
                                             __hip_bfloat16* __restrict__ out) {
  int i = (blockIdx.x * 256 + threadIdx.x) * 4;
  float4 v = *(const float4*)(in + i);
  bf4 o;
  o.v[0] = __float2bfloat16(v.x); o.v[1] = __float2bfloat16(v.y);
  o.v[2] = __float2bfloat16(v.z); o.v[3] = __float2bfloat16(v.w);
  *(bf4*)(out + i) = o;
}

// ---------------- fused attention: scores(MFMA) -> softmax -> eagg(MFMA) ----------------

__global__ __launch_bounds__(256) void k_attn_eagg(const float* __restrict__ ent,
                                                   const unsigned char* __restrict__ pmask,
                                                   const __hip_bfloat16* __restrict__ Ubf,
                                                   const float* __restrict__ cvec,
                                                   __hip_bfloat16* __restrict__ eagg) {
  __shared__ __hip_bfloat16 ent_s[kE][kD + 8];      // pitch 1032
  __shared__ __hip_bfloat16 eagg_s[kH][kD + 8];     // staged output tile
  __shared__ float sred[4][kE][kH + 1];             // per-wave partial S^T[e][h]
  __shared__ __hip_bfloat16 attn_b[kH][32];         // attn[h][e], cols 16..31 zero
  int sb = blockIdx.x;
  int s = sb >> 5, b = sb & 31;
  int t = threadIdx.x, l = t & 63, w = t >> 6;
  int quad = l >> 4, lane16 = l & 15;

  // ---- stage E x D entity tile -> LDS bf16 (coalesced 32B/lane loads) ----
  const float* src = ent + (size_t)(s * kE) * kB * kD + (size_t)b * kD;
  #pragma unroll
  for (int it = 0; it < 8; it++) {
    int i = t + it * 256;
    int e = i >> 7, f = (i & 127) * 8;
    const float4* pp = (const float4*)(src + (size_t)e * kB * kD + f);
    float4 v0 = pp[0], v1 = pp[1];
    bf8v pk;
    pk.v[0] = __float2bfloat16(v0.x); pk.v[1] = __float2bfloat16(v0.y);
    pk.v[2] = __float2bfloat16(v0.z); pk.v[3] = __float2bfloat16(v0.w);
    pk.v[4] = __float2bfloat16(v1.x); pk.v[5] = __float2bfloat16(v1.y);
    pk.v[6] = __float2bfloat16(v1.z); pk.v[7] = __float2bfloat16(v1.w);
    *(bf8v*)&ent_s[e][f] = pk;
  }
  __syncthreads();

  // ---- scores: S^T[e,h] = sum_d ent[e,d]*U[h,d]; K-split 256 per wave ----
  fvec4 sacc = {};
  #pragma unroll
  for (int ks = 0; ks < 8; ks++) {
    int k0 = w * 256 + ks * 32 + quad * 8;
    bfvec8 a = *(const bfvec8*)&ent_s[lane16][k0];                 // A[m=e][k=d]
    bfvec8 bb = *(const bfvec8*)&Ubf[(size_t)lane16 * kD + k0];    // B[k=d][n=h]
    sacc = __builtin_amdgcn_mfma_f32_16x16x32_bf16(a, bb, sacc, 0, 0, 0);
  }
  #pragma unroll
  for (int i = 0; i < 4; i++) sred[w][quad * 4 + i][lane16] = sacc[i];
  __syncthreads();

  // ---- softmax over e (thread t: h = t>>4, e = t&15) ----
  {
    int h = t >> 4, e = t & 15;
    float sc = sred[0][e][h] + sred[1][e][h] + sred[2][e][h] + sred[3][e][h] + cvec[h];
    if (pmask[(size_t)(s * kE + e) * kB + b]) sc = -INFINITY;
    float m = sc;
    #pragma unroll
    for (int o = 8; o >= 1; o >>= 1) m = fmaxf(m, __shfl_xor(m, o, 16));
    float ex = __expf(sc - m);
    float sum = ex;
    #pragma unroll
    for (int o = 8; o >= 1; o >>= 1) sum += __shfl_xor(sum, o, 16);
    attn_b[h][e] = __float2bfloat16(ex / sum);
    attn_b[h][e + 16] = __float2bfloat16(0.f);
  }
  __syncthreads();

  // ---- eagg: D[m=d16][n=h] = sum_e ent^T[d,e]*attn[h,e]; 16 d-tiles per wave ----
  bfvec8 bfrag = *(const bfvec8*)&attn_b[lane16][quad * 8];   // B[k=e][n=h], reused
  for (int tt = 0; tt < 16; tt++) {
    int dme = (w * 16 + tt) * 16 + lane16;    // m = d this lane feeds
    bfvec8 afrag = {};
    if (quad < 2) {
      #pragma unroll
      for (int j = 0; j < 8; j++)
        afrag[j] = *(const short*)&ent_s[quad * 8 + j][dme];  // A[m=d][k=e]
    }
    fvec4 acc = {};
    acc = __builtin_amdgcn_mfma_f32_16x16x32_bf16(afrag, bfrag, acc, 0, 0, 0);
    int d0 = (w * 16 + tt) * 16 + quad * 4;   // rows d = d0+i, col h = lane16
    bf4 o;
    o.v[0] = __float2bfloat16(acc[0]); o.v[1] = __float2bfloat16(acc[1]);
    o.v[2] = __float2bfloat16(acc[2]); o.v[3] = __float2bfloat16(acc[3]);
    *(bf4*)&eagg_s[lane16][d0] = o;           // stage in LDS
  }
  __syncthreads();

  // ---- coalesced eagg writeout: [sb][h][d], 16B per lane ----
  __hip_bfloat16* dstg = eagg + (size_t)sb * (kH * kD);
  #pragma unroll
  for (int it = 0; it < 8; it++) {
    int c = t + it * 256;
    int h = c >> 7, dq = (c & 127) * 8;
    *(bf8v*)(dstg + (size_t)h * kD + dq) = *(const bf8v*)&eagg_s[h][dq];
  }
}

// ---------------- bf16 MFMA GEMM (NT), 64x64 tile (small-M cases) ----------------

__device__ __forceinline__ void stage_row(const __hip_bfloat16* g, __hip_bfloat16* s) {
  *(bf8v*)s = *(const bf8v*)g;
}
__device__ __forceinline__ void stage_row(const float* g, __hip_bfloat16* s) {
  const float4* p = (const float4*)g;
  float4 v0 = p[0], v1 = p[1];
  bf8v pk;
  pk.v[0] = __float2bfloat16(v0.x); pk.v[1] = __float2bfloat16(v0.y);
  pk.v[2] = __float2bfloat16(v0.z); pk.v[3] = __float2bfloat16(v0.w);
  pk.v[4] = __float2bfloat16(v1.x); pk.v[5] = __float2bfloat16(v1.y);
  pk.v[6] = __float2bfloat16(v1.z); pk.v[7] = __float2bfloat16(v1.w);
  *(bf8v*)s = pk;
}

template <int MODE, typename TA, typename TB, typename TC>
__global__ __launch_bounds__(256) void k_gemm_mfma(
    const TA* __restrict__ Abase, int lda, long aBatch,
    const TB* __restrict__ Bbase, int ldb, long bBatch,
    TC* __restrict__ Cbase, int ldc, long cBatch,
    const float* __restrict__ bias, long biasBatch, int Ksz) {
  const TA* Ag = Abase + (size_t)blockIdx.z * aBatch;
  const TB* Bg = Bbase + (size_t)blockIdx.z * bBatch;
  TC* Cg = Cbase + (size_t)blockIdx.z * cBatch;
  const float* biasp = bias ? bias + (size_t)blockIdx.z * biasBatch : nullptr;
  const int m0 = blockIdx.x * 64, n0 = blockIdx.y * 64;
  __shared__ __hip_bfloat16 As[64][72];
  __shared__ __hip_bfloat16 Bs[64][72];
  const int t = threadIdx.x;
  const int l = t & 63, w = t >> 6;
  const int quad = l >> 4, col = l & 15;
  fvec4 acc[4] = {};
  for (int k0 = 0; k0 < Ksz; k0 += 64) {
    #pragma unroll
    for (int c = t; c < 512; c += 256) {
      int row = c >> 3, kq = (c & 7) * 8;
      stage_row(Ag + (size_t)(m0 + row) * lda + k0 + kq, &As[row][kq]);
      stage_row(Bg + (size_t)(n0 + row) * ldb + k0 + kq, &Bs[row][kq]);
    }
    __syncthreads();
    #pragma unroll
    for (int ks = 0; ks < 64; ks += 32) {
      bfvec8 a = *(const bfvec8*)&As[w * 16 + col][ks + quad * 8];
      #pragma unroll
      for (int nt = 0; nt < 4; nt++) {
        bfvec8 b = *(const bfvec8*)&Bs[nt * 16 + col][ks + quad * 8];
        acc[nt] = __builtin_amdgcn_mfma_f32_16x16x32_bf16(a, b, acc[nt], 0, 0, 0);
      }
    }
    __syncthreads();
  }
  #pragma unroll
  for (int nt = 0; nt < 4; nt++) {
    int n = n0 + nt * 16 + col;
    float bv = biasp ? biasp[n] : 0.f;
    #pragma unroll
    for (int i = 0; i < 4; i++) {
      int r = m0 + w * 16 + quad * 4 + i;
      float v = acc[nt][i] + bv;
      if constexpr (MODE == 0) ((float*)Cg)[(size_t)r * ldc + n] = v;
      else ((__hip_bfloat16*)Cg)[(size_t)r * ldc + n] = __float2bfloat16(v);
    }
  }
}

// ---------------- bf16 MFMA GEMM (NT), 128x64 tile (big GEMMs) ----------------
// wave w owns rows [w*32, w*32+32) (2 m-frags) x 4 n-frags.

template <int MODE, typename TA, typename TB, typename TC>
__global__ __launch_bounds__(256) void k_gemm_mfma2(
    const TA* __restrict__ Abase, int lda, long aBatch,
    const TB* __restrict__ Bbase, int ldb, long bBatch,
    TC* __restrict__ Cbase, int ldc, long cBatch,
    const float* __restrict__ bias, long biasBatch, int Ksz) {
  const TA* Ag = Abase + (size_t)blockIdx.z * aBatch;
  const TB* Bg = Bbase + (size_t)blockIdx.z * bBatch;
  TC* Cg = Cbase + (size_t)blockIdx.z * cBatch;
  const float* biasp = bias ? bias + (size_t)blockIdx.z * biasBatch : nullptr;
  const int m0 = blockIdx.x * 128, n0 = blockIdx.y * 64;
  __shared__ __hip_bfloat16 As[128][72];
  __shared__ __hip_bfloat16 Bs[64][72];
  const int t = threadIdx.x;
  const int l = t & 63, w = t >> 6;
  const int quad = l >> 4, col = l & 15;
  fvec4 acc[2][4] = {};
  for (int k0 = 0; k0 < Ksz; k0 += 64) {
    #pragma unroll
    for (int c = t; c < 1024; c += 256) {
      int row = c >> 3, kq = (c & 7) * 8;
      stage_row(Ag + (size_t)(m0 + row) * lda + k0 + kq, &As[row][kq]);
    }
    #pragma unroll
    for (int c = t; c < 512; c += 256) {
      int row = c >> 3, kq = (c & 7) * 8;
      stage_row(Bg + (size_t)(n0 + row) * ldb + k0 + kq, &Bs[row][kq]);
    }
    __syncthreads();
    #pragma unroll
    for (int ks = 0; ks < 64; ks += 32) {
      bfvec8 a0 = *(const bfvec8*)&As[w * 32 + col][ks + quad * 8];
      bfvec8 a1 = *(const bfvec8*)&As[w * 32 + 16 + col][ks + quad * 8];
      #pragma unroll
      for (int nt = 0; nt < 4; nt++) {
        bfvec8 b = *(const bfvec8*)&Bs[nt * 16 + col][ks + quad * 8];
        acc[0][nt] = __builtin_amdgcn_mfma_f32_16x16x32_bf16(a0, b, acc[0][nt], 0, 0, 0);
        acc[1][nt] = __builtin_amdgcn_mfma_f32_16x16x32_bf16(a1, b, acc[1][nt], 0, 0, 0);
      }
    }
    __syncthreads();
  }
  #pragma unroll
  for (int nt = 0; nt < 4; nt++) {
    int n = n0 + nt * 16 + col;
    float bv = biasp ? biasp[n] : 0.f;
    #pragma unroll
    for (int mi = 0; mi < 2; mi++) {
      #pragma unroll
      for (int i = 0; i < 4; i++) {
        int r = m0 + w * 32 + mi * 16 + quad * 4 + i;
        float v = acc[mi][nt][i] + bv;
        if constexpr (MODE == 0) ((float*)Cg)[(size_t)r * ldc + n] = v;
        else ((__hip_bfloat16*)Cg)[(size_t)r * ldc + n] = __float2bfloat16(v);
      }
    }
  }
}

extern "C" void kernel_launch(void* const* d_in, const int* in_sizes, int n_in,
                              void* d_out, int out_size, void* d_ws, size_t ws_size,
                              hipStream_t stream) {
  const float* ent            = (const float*)d_in[0];
  const unsigned char* pmask  = (const unsigned char*)d_in[1];
  const float* query          = (const float*)d_in[3];
  const float* Wk_lin         = (const float*)d_in[4];
  const float* bk_lin         = (const float*)d_in[5];
  const float* Wv_lin         = (const float*)d_in[6];
  const float* bv_lin         = (const float*)d_in[7];
  const float* Wq_in          = (const float*)d_in[8];
  const float* bq_in          = (const float*)d_in[9];
  const float* Wk_in          = (const float*)d_in[10];
  const float* bk_in          = (const float*)d_in[11];
  const float* Wv_in          = (const float*)d_in[12];
  const float* bv_in          = (const float*)d_in[13];
  const float* Wo             = (const float*)d_in[14];
  const float* bo             = (const float*)d_in[15];
  float* out = (float*)d_out;

  float* p = (float*)d_ws;
  float* qs   = p; p += 1024;            // scaled projected query
  float* wmat = p; p += 64 * kD;         // w[h,d] rows 0..15 valid
  float* cvec = p; p += 256;             // c[h]
  float* cb   = p; p += kD;              // Wv_in@bv_lin + bv_in
  __hip_bfloat16* bp = (__hip_bfloat16*)p;
  __hip_bfloat16* TT   = bp; bp += (size_t)kD * kD;    // transpose buffer (bf16)
  __hip_bfloat16* Ubf  = bp; bp += (size_t)64 * kD;    // U[h][d] bf16
  __hip_bfloat16* Mmat = bp; bp += (size_t)kD * kD;    // Wv_in @ Wv_lin bf16
  __hip_bfloat16* Wobf = bp; bp += (size_t)kD * kD;    // Wo bf16
  __hip_bfloat16* ctx2 = bp; bp += (size_t)kSB * kD;   // ctx bf16 [SB, D]
  __hip_bfloat16* eagg = bp;                           // [SB, H, D] bf16

  // ---- folded-weight precomputes ----
  k_cvt<<<kD, 256, 0, stream>>>(Wo, Wobf);
  k_rowdot<<<kD, 256, 0, stream>>>(Wq_in, query, bq_in, 0.125f, qs);
  k_w<<<64, 256, 0, stream>>>(qs, Wk_in, wmat);
  k_c<<<1, 256, 0, stream>>>(wmat, bk_lin, qs, bk_in, cvec);
  k_rowdot<<<kD, 256, 0, stream>>>(Wv_in, bv_lin, bv_in, 1.0f, cb);
  // U = wmat @ Wk_lin
  k_transpose_cvt<<<dim3(32, 32), dim3(32, 8), 0, stream>>>(Wk_lin, TT);
  k_gemm_mfma<2><<<dim3(1, 16, 1), 256, 0, stream>>>(
      wmat, kD, 0L, TT, kD, 0L, Ubf, kD, 0L, (const float*)nullptr, 0L, kD);
  // M = Wv_in @ Wv_lin
  k_transpose_cvt<<<dim3(32, 32), dim3(32, 8), 0, stream>>>(Wv_lin, TT);
  k_gemm_mfma2<2><<<dim3(8, 16, 1), 256, 0, stream>>>(
      Wv_in, kD, 0L, TT, kD, 0L, Mmat, kD, 0L, (const float*)nullptr, 0L, kD);

  // ---- main pipeline ----
  k_attn_eagg<<<kSB, 256, 0, stream>>>(ent, pmask, Ubf, cvec, eagg);
  // ctx[sb, h*64+j] = M_h @ eagg[sb,h,:] + cb   (batched over h = z), bf16 out
  k_gemm_mfma2<2><<<dim3(kSB / 128, 1, kH), 256, 0, stream>>>(
      eagg, kH * kD, (long)kD, Mmat, kD, (long)(kHD * kD),
      ctx2, kD, (long)kHD, cb, (long)kHD, kD);
  // out = ctx @ Wo^T + bo
  k_gemm_mfma2<0><<<dim3(kSB / 128, kD / 64, 1), 256, 0, stream>>>(
      ctx2, kD, 0L, Wobf, kD, 0L, out, kD, 0L, bo, 0L, kD);
}

// Round 5
// 355.431 us; speedup vs baseline: 1.1789x; 1.1789x over previous
//
#include <hip/hip_runtime.h>
#include <hip/hip_bf16.h>

constexpr int kD  = 1024;
constexpr int kH  = 16;
constexpr int kHD = 64;
constexpr int kS  = 64;
constexpr int kE  = 16;
constexpr int kB  = 32;
constexpr int kSB = kS * kB;   // 2048 (s,b) pairs

typedef __attribute__((ext_vector_type(8))) short bfvec8;   // 8 bf16 (4 VGPRs)
typedef __attribute__((ext_vector_type(4))) float fvec4;    // MFMA acc

struct __align__(8)  bf4  { __hip_bfloat16 v[4]; };
struct __align__(16) bf8v { __hip_bfloat16 v[8]; };

// ---------------- precompute kernels ----------------

// blocks 0..1023: qs[j]  = (Wq_in[j,:]·query + bq_in[j]) * 0.125
// blocks 1024..2047: cb[j] = Wv_in[j,:]·bv_lin + bv_in[j]
// block 0 also zeroes cvec (consumed via atomics by k_w2, next kernel).
__global__ __launch_bounds__(256) void k_pre(const float* __restrict__ Wq_in,
                                             const float* __restrict__ query,
                                             const float* __restrict__ bq_in,
                                             const float* __restrict__ Wv_in,
                                             const float* __restrict__ bv_lin,
                                             const float* __restrict__ bv_in,
                                             float* __restrict__ qs,
                                             float* __restrict__ cb,
                                             float* __restrict__ cvec) {
  int j = blockIdx.x, t = threadIdx.x;
  if (j == 0 && t < 16) cvec[t] = 0.f;
  const float *W, *vec, *bias;
  float scale;
  float* outp;
  int row;
  if (j < 1024) { W = Wq_in; vec = query;  bias = bq_in; scale = 0.125f; outp = qs; row = j; }
  else          { W = Wv_in; vec = bv_lin; bias = bv_in; scale = 1.0f;   outp = cb; row = j - 1024; }
  const float4* w4 = (const float4*)(W + (size_t)row * kD);
  const float4* v4 = (const float4*)vec;
  float4 a = w4[t], b = v4[t];
  float acc = a.x * b.x + a.y * b.y + a.z * b.z + a.w * b.w;
  #pragma unroll
  for (int o = 32; o >= 1; o >>= 1) acc += __shfl_xor(acc, o);
  __shared__ float red[4];
  if ((t & 63) == 0) red[t >> 6] = acc;
  __syncthreads();
  if (t == 0) outp[row] = (red[0] + red[1] + red[2] + red[3] + bias[row]) * scale;
}

// wmat[h,d] = sum_j qs[h*64+j] * Wk_in[h*64+j, d]  (rows 0..15 of 64-row buf)
// also accumulates cvec[h] += wmat[h,d]*bk_lin[d] (+ qs·bk_in for d<64) via atomics.
__global__ __launch_bounds__(256) void k_w2(const float* __restrict__ qs,
                                            const float* __restrict__ Wk_in,
                                            const float* __restrict__ bk_lin,
                                            const float* __restrict__ bk_in,
                                            float* __restrict__ wmat,
                                            float* __restrict__ cvec) {
  int tid = blockIdx.x * 256 + threadIdx.x;
  int h = tid >> 10, d = tid & (kD - 1);
  float acc = 0.f;
  #pragma unroll 8
  for (int j = 0; j < kHD; j++)
    acc = fmaf(qs[h * kHD + j], Wk_in[(size_t)(h * kHD + j) * kD + d], acc);
  wmat[(size_t)h * kD + d] = acc;
  float val = acc * bk_lin[d];
  if (d < kHD) val += qs[h * kHD + d] * bk_in[h * kHD + d];
  #pragma unroll
  for (int o = 32; o >= 1; o >>= 1) val += __shfl_xor(val, o);
  if ((threadIdx.x & 63) == 0) atomicAdd(&cvec[h], val);
}

// plain f32 -> bf16 convert, 4 elems/thread
__global__ __launch_bounds__(256) void k_cvt(const float* __restrict__ in,
                                             __hip_bfloat16* __restrict__ out) {
  int i = (blockIdx.x * 256 + threadIdx.x) * 4;
  float4 v = *(const float4*)(in + i);
  bf4 o;
  o.v[0] = __float2bfloat16(v.x); o.v[1] = __float2bfloat16(v.y);
  o.v[2] = __float2bfloat16(v.z); o.v[3] = __float2bfloat16(v.w);
  *(bf4*)(out + i) = o;
}

// ---------------- fused attention: scores(MFMA) -> softmax -> eagg(MFMA) ----------------
// (round-3 proven version: 38.7 KB LDS -> 4 blocks/CU)

__global__ __launch_bounds__(256) void k_attn_eagg(const float* __restrict__ ent,
                                                   const unsigned char* __restrict__ pmask,
                                                   const __hip_bfloat16* __restrict__ Ubf,
                                                   const float* __restrict__ cvec,
                                                   __hip_bfloat16* __restrict__ eagg) {
  __shared__ __hip_bfloat16 ent_s[kE][kD + 8];      // pitch 1032
  __shared__ float sred[4][kE][kH + 1];             // per-wave partial S^T[e][h]
  __shared__ __hip_bfloat16 attn_b[kH][32];         // attn[h][e], cols 16..31 zero
  int sb = blockIdx.x;
  int s = sb >> 5, b = sb & 31;
  int t = threadIdx.x, l = t & 63, w = t >> 6;
  int quad = l >> 4, lane16 = l & 15;

  // ---- stage E x D entity tile -> LDS bf16 ----
  const float* src = ent + (size_t)(s * kE) * kB * kD + (size_t)b * kD;
  #pragma unroll
  for (int it = 0; it < 8; it++) {
    int i = t + it * 256;
    int e = i >> 7, f = (i & 127) * 8;
    const float4* pp = (const float4*)(src + (size_t)e * kB * kD + f);
    float4 v0 = pp[0], v1 = pp[1];
    bf8v pk;
    pk.v[0] = __float2bfloat16(v0.x); pk.v[1] = __float2bfloat16(v0.y);
    pk.v[2] = __float2bfloat16(v0.z); pk.v[3] = __float2bfloat16(v0.w);
    pk.v[4] = __float2bfloat16(v1.x); pk.v[5] = __float2bfloat16(v1.y);
    pk.v[6] = __float2bfloat16(v1.z); pk.v[7] = __float2bfloat16(v1.w);
    *(bf8v*)&ent_s[e][f] = pk;
  }
  __syncthreads();

  // ---- scores: S^T[e,h] = sum_d ent[e,d]*U[h,d]; K-split 256 per wave ----
  fvec4 sacc = {};
  #pragma unroll
  for (int ks = 0; ks < 8; ks++) {
    int k0 = w * 256 + ks * 32 + quad * 8;
    bfvec8 a = *(const bfvec8*)&ent_s[lane16][k0];
    bfvec8 bb = *(const bfvec8*)&Ubf[(size_t)lane16 * kD + k0];
    sacc = __builtin_amdgcn_mfma_f32_16x16x32_bf16(a, bb, sacc, 0, 0, 0);
  }
  #pragma unroll
  for (int i = 0; i < 4; i++) sred[w][quad * 4 + i][lane16] = sacc[i];
  __syncthreads();

  // ---- softmax over e (thread t: h = t>>4, e = t&15) ----
  {
    int h = t >> 4, e = t & 15;
    float sc = sred[0][e][h] + sred[1][e][h] + sred[2][e][h] + sred[3][e][h] + cvec[h];
    if (pmask[(size_t)(s * kE + e) * kB + b]) sc = -INFINITY;
    float m = sc;
    #pragma unroll
    for (int o = 8; o >= 1; o >>= 1) m = fmaxf(m, __shfl_xor(m, o, 16));
    float ex = __expf(sc - m);
    float sum = ex;
    #pragma unroll
    for (int o = 8; o >= 1; o >>= 1) sum += __shfl_xor(sum, o, 16);
    attn_b[h][e] = __float2bfloat16(ex / sum);
    attn_b[h][e + 16] = __float2bfloat16(0.f);
  }
  __syncthreads();

  // ---- eagg: D[m=d16][n=h] = sum_e ent^T[d,e]*attn[h,e]; 16 d-tiles per wave ----
  bfvec8 bfrag = *(const bfvec8*)&attn_b[lane16][quad * 8];
  __hip_bfloat16* dst = eagg + (size_t)sb * (kH * kD);
  for (int tt = 0; tt < 16; tt++) {
    int dme = (w * 16 + tt) * 16 + lane16;
    bfvec8 afrag = {};
    if (quad < 2) {
      #pragma unroll
      for (int j = 0; j < 8; j++)
        afrag[j] = *(const short*)&ent_s[quad * 8 + j][dme];
    }
    fvec4 acc = {};
    acc = __builtin_amdgcn_mfma_f32_16x16x32_bf16(afrag, bfrag, acc, 0, 0, 0);
    int d0 = (w * 16 + tt) * 16 + quad * 4;
    bf4 o;
    o.v[0] = __float2bfloat16(acc[0]); o.v[1] = __float2bfloat16(acc[1]);
    o.v[2] = __float2bfloat16(acc[2]); o.v[3] = __float2bfloat16(acc[3]);
    *(bf4*)&dst[(size_t)lane16 * kD + d0] = o;
  }
}

// ---------------- staging helpers ----------------

__device__ __forceinline__ void stage_row(const __hip_bfloat16* g, __hip_bfloat16* s) {
  *(bf8v*)s = *(const bf8v*)g;
}
__device__ __forceinline__ void stage_row(const float* g, __hip_bfloat16* s) {
  const float4* p = (const float4*)g;
  float4 v0 = p[0], v1 = p[1];
  bf8v pk;
  pk.v[0] = __float2bfloat16(v0.x); pk.v[1] = __float2bfloat16(v0.y);
  pk.v[2] = __float2bfloat16(v0.z); pk.v[3] = __float2bfloat16(v0.w);
  pk.v[4] = __float2bfloat16(v1.x); pk.v[5] = __float2bfloat16(v1.y);
  pk.v[6] = __float2bfloat16(v1.z); pk.v[7] = __float2bfloat16(v1.w);
  *(bf8v*)s = pk;
}

// ---------------- bf16 MFMA GEMM (NT), 64x64 tile ----------------
// MODE 0: f32 out. MODE 2: bf16 out. Bias added if non-null.

template <int MODE, typename TA, typename TB, typename TC>
__global__ __launch_bounds__(256) void k_gemm_mfma(
    const TA* __restrict__ Abase, int lda, long aBatch,
    const TB* __restrict__ Bbase, int ldb, long bBatch,
    TC* __restrict__ Cbase, int ldc, long cBatch,
    const float* __restrict__ bias, long biasBatch, int Ksz) {
  const TA* Ag = Abase + (size_t)blockIdx.z * aBatch;
  const TB* Bg = Bbase + (size_t)blockIdx.z * bBatch;
  TC* Cg = Cbase + (size_t)blockIdx.z * cBatch;
  const float* biasp = bias ? bias + (size_t)blockIdx.z * biasBatch : nullptr;
  const int m0 = blockIdx.x * 64, n0 = blockIdx.y * 64;
  __shared__ __hip_bfloat16 As[64][72];
  __shared__ __hip_bfloat16 Bs[64][72];
  const int t = threadIdx.x;
  const int l = t & 63, w = t >> 6;
  const int quad = l >> 4, col = l & 15;
  fvec4 acc[4] = {};
  for (int k0 = 0; k0 < Ksz; k0 += 64) {
    #pragma unroll
    for (int c = t; c < 512; c += 256) {
      int row = c >> 3, kq = (c & 7) * 8;
      stage_row(Ag + (size_t)(m0 + row) * lda + k0 + kq, &As[row][kq]);
      stage_row(Bg + (size_t)(n0 + row) * ldb + k0 + kq, &Bs[row][kq]);
    }
    __syncthreads();
    #pragma unroll
    for (int ks = 0; ks < 64; ks += 32) {
      bfvec8 a = *(const bfvec8*)&As[w * 16 + col][ks + quad * 8];
      #pragma unroll
      for (int nt = 0; nt < 4; nt++) {
        bfvec8 b = *(const bfvec8*)&Bs[nt * 16 + col][ks + quad * 8];
        acc[nt] = __builtin_amdgcn_mfma_f32_16x16x32_bf16(a, b, acc[nt], 0, 0, 0);
      }
    }
    __syncthreads();
  }
  #pragma unroll
  for (int nt = 0; nt < 4; nt++) {
    int n = n0 + nt * 16 + col;
    float bv = biasp ? biasp[n] : 0.f;
    #pragma unroll
    for (int i = 0; i < 4; i++) {
      int r = m0 + w * 16 + quad * 4 + i;
      float v = acc[nt][i] + bv;
      if constexpr (MODE == 0) ((float*)Cg)[(size_t)r * ldc + n] = v;
      else ((__hip_bfloat16*)Cg)[(size_t)r * ldc + n] = __float2bfloat16(v);
    }
  }
}

// ---------------- bf16 MFMA GEMM (NN, f32 inputs, bf16 out), 64x64 tile ----------------
// C[m,n] = sum_k A[m,k]*B[k,n].  B transposed+converted during LDS staging.

__global__ __launch_bounds__(256) void k_gemm_nn(
    const float* __restrict__ Ag, int lda,
    const float* __restrict__ Bg, int ldb,
    __hip_bfloat16* __restrict__ Cg, int ldc, int Ksz) {
  const int m0 = blockIdx.x * 64, n0 = blockIdx.y * 64;
  __shared__ __hip_bfloat16 As[64][72];
  __shared__ __hip_bfloat16 Bs[64][72];
  const int t = threadIdx.x;
  const int l = t & 63, w = t >> 6;
  const int quad = l >> 4, col = l & 15;
  fvec4 acc[4] = {};
  for (int k0 = 0; k0 < Ksz; k0 += 64) {
    #pragma unroll
    for (int c = t; c < 512; c += 256) {
      int row = c >> 3, kq = (c & 7) * 8;
      stage_row(Ag + (size_t)(m0 + row) * lda + k0 + kq, &As[row][kq]);
      // B row k0+row, cols n0+kq..+7 -> Bs[n][k] (scalar transposed writes)
      const float4* pb = (const float4*)(Bg + (size_t)(k0 + row) * ldb + n0 + kq);
      float4 b0 = pb[0], b1 = pb[1];
      Bs[kq + 0][row] = __float2bfloat16(b0.x);
      Bs[kq + 1][row] = __float2bfloat16(b0.y);
      Bs[kq + 2][row] = __float2bfloat16(b0.z);
      Bs[kq + 3][row] = __float2bfloat16(b0.w);
      Bs[kq + 4][row] = __float2bfloat16(b1.x);
      Bs[kq + 5][row] = __float2bfloat16(b1.y);
      Bs[kq + 6][row] = __float2bfloat16(b1.z);
      Bs[kq + 7][row] = __float2bfloat16(b1.w);
    }
    __syncthreads();
    #pragma unroll
    for (int ks = 0; ks < 64; ks += 32) {
      bfvec8 a = *(const bfvec8*)&As[w * 16 + col][ks + quad * 8];
      #pragma unroll
      for (int nt = 0; nt < 4; nt++) {
        bfvec8 b = *(const bfvec8*)&Bs[nt * 16 + col][ks + quad * 8];
        acc[nt] = __builtin_amdgcn_mfma_f32_16x16x32_bf16(a, b, acc[nt], 0, 0, 0);
      }
    }
    __syncthreads();
  }
  #pragma unroll
  for (int nt = 0; nt < 4; nt++) {
    int n = n0 + nt * 16 + col;
    #pragma unroll
    for (int i = 0; i < 4; i++) {
      int r = m0 + w * 16 + quad * 4 + i;
      Cg[(size_t)r * ldc + n] = __float2bfloat16(acc[nt][i]);
    }
  }
}

extern "C" void kernel_launch(void* const* d_in, const int* in_sizes, int n_in,
                              void* d_out, int out_size, void* d_ws, size_t ws_size,
                              hipStream_t stream) {
  const float* ent            = (const float*)d_in[0];
  const unsigned char* pmask  = (const unsigned char*)d_in[1];
  const float* query          = (const float*)d_in[3];
  const float* Wk_lin         = (const float*)d_in[4];
  const float* bk_lin         = (const float*)d_in[5];
  const float* Wv_lin         = (const float*)d_in[6];
  const float* bv_lin         = (const float*)d_in[7];
  const float* Wq_in          = (const float*)d_in[8];
  const float* bq_in          = (const float*)d_in[9];
  const float* Wk_in          = (const float*)d_in[10];
  const float* bk_in          = (const float*)d_in[11];
  const float* Wv_in          = (const float*)d_in[12];
  const float* bv_in          = (const float*)d_in[13];
  const float* Wo             = (const float*)d_in[14];
  const float* bo             = (const float*)d_in[15];
  float* out = (float*)d_out;

  float* p = (float*)d_ws;
  float* qs   = p; p += 1024;            // scaled projected query
  float* wmat = p; p += 64 * kD;         // w[h,d] rows 0..15 valid
  float* cvec = p; p += 256;             // c[h]
  float* cb   = p; p += kD;              // Wv_in@bv_lin + bv_in
  __hip_bfloat16* bp = (__hip_bfloat16*)p;
  __hip_bfloat16* Ubf  = bp; bp += (size_t)64 * kD;    // U[h][d] bf16 (rows 0..15 valid)
  __hip_bfloat16* Mmat = bp; bp += (size_t)kD * kD;    // Wv_in @ Wv_lin bf16
  __hip_bfloat16* Wobf = bp; bp += (size_t)kD * kD;    // Wo bf16
  __hip_bfloat16* ctx2 = bp; bp += (size_t)kSB * kD;   // ctx bf16 [SB, D]
  __hip_bfloat16* eagg = bp;                           // [SB, H, D] bf16

  // ---- folded-weight precomputes (8 dispatches total incl. main pipeline) ----
  k_pre<<<2048, 256, 0, stream>>>(Wq_in, query, bq_in, Wv_in, bv_lin, bv_in, qs, cb, cvec);
  k_w2<<<64, 256, 0, stream>>>(qs, Wk_in, bk_lin, bk_in, wmat, cvec);
  k_cvt<<<1024, 256, 0, stream>>>(Wo, Wobf);
  // U = wmat @ Wk_lin   (NN, no transpose kernel)
  k_gemm_nn<<<dim3(1, 16, 1), 256, 0, stream>>>(wmat, kD, Wk_lin, kD, Ubf, kD, kD);
  // M = Wv_in @ Wv_lin  (NN)
  k_gemm_nn<<<dim3(16, 16, 1), 256, 0, stream>>>(Wv_in, kD, Wv_lin, kD, Mmat, kD, kD);

  // ---- main pipeline ----
  k_attn_eagg<<<kSB, 256, 0, stream>>>(ent, pmask, Ubf, cvec, eagg);
  // ctx[sb, h*64+j] = M_h @ eagg[sb,h,:] + cb   (batched over h = z), bf16 out
  k_gemm_mfma<2><<<dim3(kSB / 64, 1, kH), 256, 0, stream>>>(
      eagg, kH * kD, (long)kD, Mmat, kD, (long)(kHD * kD),
      ctx2, kD, (long)kHD, cb, (long)kHD, kD);
  // out = ctx @ Wo^T + bo
  k_gemm_mfma<0><<<dim3(kSB / 64, kD / 64, 1), 256, 0, stream>>>(
      ctx2, kD, 0L, Wobf, kD, 0L, out, kD, 0L, bo, 0L, kD);
}